// Round 9
// baseline (333.010 us; speedup 1.0000x reference)
//
#include <hip/hip_runtime.h>
#include <math.h>

#define NVARS 11
#define NUMT  100
#define NOBS  10
#define MAXIT 50

// workspace layout (floats) — identical to r1..r8
#define E_OFF    0      // inv_init[:11,11:17]  11x6
#define F_OFF    66     // inv_opt[:11,:11]     11x11
#define G4_OFF   187    // inv_opt[:11,11:15]   11x4
#define GP_OFF   231    // P^T P                11x11
#define GPD_OFF  352    // Pd^T Pd
#define GPDD_OFF 473    // Pdd^T Pdd
#define WS_FLOATS 594

#define BSTRIDE 308     // row stride (16B aligned)

__device__ void gj_inv(double (*aug)[34], int N, double* fac, int* piv, int tid, int nthr)
{
    for (int k = 0; k < N; ++k) {
        if (tid == 0) {
            int p = k; double best = fabs(aug[k][k]);
            for (int r = k + 1; r < N; ++r) { double v = fabs(aug[r][k]); if (v > best) { best = v; p = r; } }
            *piv = p;
        }
        __syncthreads();
        int p = *piv;
        if (p != k) {
            for (int c = tid; c < 2 * N; c += nthr) { double t = aug[k][c]; aug[k][c] = aug[p][c]; aug[p][c] = t; }
        }
        __syncthreads();
        double pv = aug[k][k];
        __syncthreads();
        for (int c = tid; c < 2 * N; c += nthr) aug[k][c] /= pv;
        __syncthreads();
        if (tid < N) fac[tid] = aug[tid][k];
        __syncthreads();
        for (int idx = tid; idx < N * 2 * N; idx += nthr) {
            int r = idx / (2 * N), c = idx % (2 * N);
            if (r != k) aug[r][c] -= fac[r] * aug[k][c];
        }
        __syncthreads();
    }
}

__global__ __launch_bounds__(128) void setup_kernel(const float* __restrict__ P,
                                                    const float* __restrict__ Pd,
                                                    const float* __restrict__ Pdd,
                                                    float* __restrict__ ws)
{
    __shared__ double G[3][NVARS][NVARS];
    __shared__ double aug[17][34];
    __shared__ double fac[17];
    __shared__ int piv;
    const int tid = threadIdx.x, nthr = 128;

    for (int idx = tid; idx < 3 * 121; idx += nthr) {
        int q = idx / 121, rem = idx % 121, r = rem / 11, c = rem % 11;
        const float* B = (q == 0) ? P : (q == 1) ? Pd : Pdd;
        double s = 0.0;
        for (int t = 0; t < NUMT; ++t) s += (double)B[t * 11 + r] * (double)B[t * 11 + c];
        G[q][r][c] = s;
    }
    __syncthreads();
    for (int idx = tid; idx < 3 * 121; idx += nthr) ws[GP_OFF + idx] = (float)((&G[0][0][0])[idx]);

    for (int idx = tid; idx < 17 * 34; idx += nthr) aug[idx / 34][idx % 34] = 0.0;
    __syncthreads();
    for (int idx = tid; idx < 121; idx += nthr) aug[idx / 11][idx % 11] = G[2][idx / 11][idx % 11];
    if (tid < 66) {
        int r = tid / 11, j = tid % 11;
        const float* src = (r == 0) ? P : (r == 1) ? Pd : (r == 2) ? (P + 99 * 11) : (r == 3) ? (Pd + 99 * 11)
                           : (r == 4) ? (P + 49 * 11) : (P + 74 * 11);
        double v = (double)src[j];
        aug[j][11 + r] = v;
        aug[11 + r][j] = v;
    }
    if (tid < 17) aug[tid][17 + tid] = 1.0;
    __syncthreads();
    gj_inv(aug, 17, fac, &piv, tid, nthr);
    if (tid < 66) { int j = tid / 6, k = tid % 6; ws[E_OFF + tid] = (float)aug[j][17 + 11 + k]; }
    __syncthreads();

    for (int idx = tid; idx < 17 * 34; idx += nthr) aug[idx / 34][idx % 34] = 0.0;
    __syncthreads();
    for (int idx = tid; idx < 121; idx += nthr) {
        int r = idx / 11, c = idx % 11;
        aug[r][c] = 11.0 * G[0][r][c] + G[1][r][c] + G[2][r][c] + ((r == c) ? 1.0 : 0.0);
    }
    if (tid < 44) {
        int r = tid / 11, j = tid % 11;
        const float* src = (r == 0) ? P : (r == 1) ? Pd : (r == 2) ? (P + 99 * 11) : (Pd + 99 * 11);
        double v = (double)src[j];
        aug[j][11 + r] = v;
        aug[11 + r][j] = v;
    }
    if (tid < 15) aug[tid][15 + tid] = 1.0;
    __syncthreads();
    gj_inv(aug, 15, fac, &piv, tid, nthr);
    if (tid < 121) { int j = tid / 11, k = tid % 11; ws[F_OFF + tid] = (float)aug[j][15 + k]; }
    if (tid < 44)  { int j = tid / 4,  k = tid % 4;  ws[G4_OFF + tid] = (float)aug[j][15 + 11 + k]; }
}

__device__ __forceinline__ float sbcast(float v) {
    return __int_as_float(__builtin_amdgcn_readfirstlane(__float_as_int(v)));
}

// solve: 1 element per 256-thread block, grid 2048; balanced wave layout:
//   wave0: A(t=0..63)   wave1: A(t=64..99)
//   wave2: Gram (||A) + B tasks 0..32
//   wave3: B tasks 33..65 + C + D (+ c_bar init, out write)
// __launch_bounds__(256,6): waves/EU cap 6 (75% occ), VGPR budget ~85 -> no spill
// (evidence: (256,8) => VGPR 32 + 43-67MB scratch spill; (256,4) => occ capped 50%)
__global__ __launch_bounds__(256, 6) void solve_kernel(
    const float* __restrict__ P, const float* __restrict__ Pd, const float* __restrict__ Pdd,
    const float* __restrict__ ise, const float* __restrict__ term, const float* __restrict__ via,
    const float* __restrict__ obs, const float* __restrict__ tgt, const float* __restrict__ dtb,
    const float* __restrict__ ws, float* __restrict__ out)
{
    __shared__ __align__(16) float sBc[NVARS][BSTRIDE];   // [j][q*100+t]
    __shared__ __align__(16) float wbc[2][BSTRIDE];       // [axis][q*100+t]
    __shared__ float cst[WS_FLOATS];
    __shared__ float sd456[3][24];    // Gram matvec results (wave 2)
    __shared__ float Dred[6][12];
    __shared__ float mlin[2][12];
    __shared__ float scoef[2][12];
    __shared__ float beqs[2][4];
    __shared__ float sobs[2][NOBS];
    __shared__ float stgt[6];

    const int tid = threadIdx.x;
    const int b = blockIdx.x;

    // ---- stage LDS
    for (int idx = tid; idx < NVARS * BSTRIDE; idx += 256) {
        int j = idx / BSTRIDE, r = idx % BSTRIDE;
        float v = 0.f;
        if (r < 300) {
            int q = r / 100, t = r % 100;
            const float* Bq = (q == 0) ? P : (q == 1) ? Pd : Pdd;
            v = Bq[t * 11 + j];
        }
        sBc[j][r] = v;
    }
    for (int idx = tid; idx < WS_FLOATS; idx += 256) cst[idx] = ws[idx];
    if (tid < 20) sobs[tid / 10][tid % 10] = obs[b * 20 + tid];
    if (tid == 0) {
        beqs[0][0] = 0.f; beqs[0][1] = ise[b*4+2]; beqs[0][2] = term[b*4+0]; beqs[0][3] = term[b*4+2];
        beqs[1][0] = 0.f; beqs[1][1] = ise[b*4+3]; beqs[1][2] = term[b*4+1]; beqs[1][3] = term[b*4+3];
        stgt[0] = tgt[b*4+0]; stgt[1] = tgt[b*4+2];
        stgt[2] = tgt[b*4+1]; stgt[3] = tgt[b*4+3];
        stgt[4] = dtb[b*2+0]; stgt[5] = dtb[b*2+1];
    }
    __syncthreads();

    // lane roles
    const int l2 = tid - 128;   // wave-2 local (Gram: l2<22, B: l2<33)
    const int l3 = tid - 192;   // wave-3 local (B: l3<33 -> tasks 33.., C/D: l3<22)
    const int ca = (l3 >= 0) ? l3 / 11 : 0, cj = (l3 >= 0) ? l3 % 11 : 0;

    // init c_bar (r1-verbatim) on wave 3
    float lm = 0.f, cb = 0.f;
    if (l3 >= 0 && l3 < 22) {
        float bi0 = 0.f, bi1 = beqs[ca][1], bi2 = beqs[ca][2], bi3 = beqs[ca][3];
        float bi4 = via[b*4 + 2*ca + 0], bi5 = via[b*4 + 2*ca + 1];
        const float* E = &cst[E_OFF + cj * 6];
        float s = E[0]*bi0 + E[1]*bi1 + E[2]*bi2 + E[3]*bi3 + E[4]*bi4 + E[5]*bi5;
        cb = s; scoef[ca][cj] = s;
    }

    // ---- iteration-invariant caches (phase A lanes): full basis rows in VGPRs
    float rP[NVARS], rPd[NVARS], rPdd[NVARS];
    {
        const int t = (tid < NUMT) ? tid : 0;
        #pragma unroll
        for (int k = 0; k < NVARS; ++k) {
            rP[k]   = sBc[k][t];
            rPd[k]  = sBc[k][t + 100];
            rPdd[k] = sBc[k][t + 200];
        }
    }
    float obx[NOBS], oby[NOBS];   // wave-uniform -> SGPRs
    #pragma unroll
    for (int o = 0; o < NOBS; ++o) {
        obx[o] = sbcast(sobs[0][o]);
        oby[o] = sbcast(sobs[1][o]);
    }
    const float tg0 = sbcast(stgt[0]), tg1 = sbcast(stgt[1]);
    const float tg2 = sbcast(stgt[2]), tg3 = sbcast(stgt[3]);
    const float tg4 = sbcast(stgt[4]), tg5 = sbcast(stgt[5]);

    float* pwA = &wbc[0][tid];               // + axis*BSTRIDE + q*100

    // phase-B task: wave2 lanes 0..32 -> tasks 0..32; wave3 lanes 0..32 -> tasks 33..65
    int btask = -1;
    if (l2 >= 0 && l2 < 33) btask = l2;
    if (l3 >= 0 && l3 < 33) btask = l3 + 33;
    const int wi = (btask >= 0) ? btask % 6 : 0;
    const int bjj = (btask >= 0) ? btask / 6 : 0;
    const float4* pbB = (const float4*)(&sBc[0][0] + bjj * BSTRIDE + (wi % 3) * 100);
    const float4* pwB = (const float4*)(&wbc[wi / 3][(wi % 3) * 100]);
    __syncthreads();

    for (int it = 0; it < MAXIT; ++it) {
        // ---- phase A (waves 0,1: tid<100) — r4-verbatim math
        if (tid < NUMT) {
            float x=0,y=0,xd=0,yd=0,xdd=0,ydd=0;
            #pragma unroll
            for (int k = 0; k < NVARS; ++k) {
                float cxk = scoef[0][k], cyk = scoef[1][k];
                x += cxk*rP[k];   y += cyk*rP[k];
                xd += cxk*rPd[k]; yd += cyk*rPd[k];
                xdd += cxk*rPdd[k]; ydd += cyk*rPdd[k];
            }
            float Sbx = 0.f, Sby = 0.f;
            #pragma unroll
            for (int o = 0; o < NOBS; ++o) {
                float dx = x - obx[o], dy = y - oby[o];
                float r2 = dx*dx + dy*dy;
                float f  = fmaxf(1.0f, 0.4f * rsqrtf(fmaxf(r2, 1e-30f)));
                Sbx += fmaf(dx, f, obx[o]);
                Sby += fmaf(dy, f, oby[o]);
            }
            float rv = sqrtf(xd*xd + yd*yd);
            float fv = fminf(fmaxf(rv, 0.1f), 2.0f) / fmaxf(rv, 1e-30f);
            float ra = sqrtf(xdd*xdd + ydd*ydd);
            float fa = fminf(ra, 2.0f) / fmaxf(ra, 1e-30f);
            float tt = (float)tid * (5.0f / 99.0f);
            float xt = tg0 + tg1*tt, yt = tg2 + tg3*tt;
            float wct = x - xt, wst = y - yt;
            float rt = sqrtf(wct*wct + wst*wst);
            float ftg = fminf(fmaxf(rt, tg4), tg5) / fmaxf(rt, 1e-30f);
            pwA[0]   = Sbx + xt + wct*ftg;
            pwA[100] = xd * fv;
            pwA[200] = xdd * fa;
            pwA[BSTRIDE]       = Sby + yt + wst*ftg;
            pwA[BSTRIDE + 100] = yd * fv;
            pwA[BSTRIDE + 200] = ydd * fa;
        }
        // ---- wave 2 concurrently: Gram matvecs from prev coef (bit-exact)
        if (l2 >= 0 && l2 < 22) {
            const int ga = l2 / 11, gj = l2 % 11;
            float d4=0.f, d5=0.f, d6=0.f;
            #pragma unroll
            for (int k = 0; k < 11; ++k) {
                float ck = scoef[ga][k];
                d4 += ck * cst[GP_OFF   + k*11 + gj];
                d5 += ck * cst[GPD_OFF  + k*11 + gj];
                d6 += ck * cst[GPDD_OFF + k*11 + gj];
            }
            sd456[0][l2] = d4; sd456[1][l2] = d5; sd456[2][l2] = d6;
        }
        __syncthreads();

        // ---- phase B (waves 2,3): 66 float4 dots, exact t-order
        if (btask >= 0) {
            float s = 0.f;
            #pragma unroll
            for (int i = 0; i < 25; ++i) {
                float4 a = pbB[i], w = pwB[i];
                s += w.x * a.x; s += w.y * a.y; s += w.z * a.z; s += w.w * a.w;
            }
            Dred[wi][bjj] = s;
        }
        __syncthreads();

        // ---- phase C (wave 3, l3<22): combine
        if (l3 >= 0 && l3 < 22) {
            float d4 = sd456[0][l3], d5 = sd456[1][l3], d6 = sd456[2][l3];
            int i0 = 3*ca;
            float D0 = Dred[i0][cj], D1 = Dred[i0+1][cj], D2 = Dred[i0+2][cj];
            lm -= (11.f*d4 - D0) + (d5 - D1) + (d6 - D2);
            mlin[ca][cj] = lm + D0 + D1 + D2 + cb;
        }
        // no barrier: C->D producers/consumers are lanes l3<22 of wave 3

        // ---- phase D (wave 3, l3<22)
        if (l3 >= 0 && l3 < 22) {
            float s = 0.f;
            #pragma unroll
            for (int k = 0; k < 11; ++k) s += cst[F_OFF + cj*11 + k] * mlin[ca][k];
            #pragma unroll
            for (int k = 0; k < 4; ++k)  s += cst[G4_OFF + cj*4 + k] * beqs[ca][k];
            scoef[ca][cj] = s;
        }
        __syncthreads();
    }

    if (l3 >= 0 && l3 < 22) out[b * 22 + l3] = scoef[ca][cj];
}

extern "C" void kernel_launch(void* const* d_in, const int* in_sizes, int n_in,
                              void* d_out, int out_size, void* d_ws, size_t ws_size,
                              hipStream_t stream)
{
    const float* P    = (const float*)d_in[0];
    const float* Pd   = (const float*)d_in[1];
    const float* Pdd  = (const float*)d_in[2];
    const float* ise  = (const float*)d_in[3];
    const float* term = (const float*)d_in[4];
    const float* via  = (const float*)d_in[5];
    const float* obs  = (const float*)d_in[6];
    const float* tgt  = (const float*)d_in[7];
    const float* dtb  = (const float*)d_in[8];
    float* ws  = (float*)d_ws;
    float* out = (float*)d_out;

    const int B = in_sizes[3] / 4;   // 2048

    hipLaunchKernelGGL(setup_kernel, dim3(1), dim3(128), 0, stream, P, Pd, Pdd, ws);
    hipLaunchKernelGGL(solve_kernel, dim3(B), dim3(256), 0, stream,
                       P, Pd, Pdd, ise, term, via, obs, tgt, dtb, ws, out);
}

// Round 10
// 296.702 us; speedup vs baseline: 1.1224x; 1.1224x over previous
//
#include <hip/hip_runtime.h>
#include <math.h>

#define NVARS 11
#define NUMT  100
#define NOBS  10
#define MAXIT 50

// workspace layout (floats) — identical to r1..r9
#define E_OFF    0      // inv_init[:11,11:17]  11x6
#define F_OFF    66     // inv_opt[:11,:11]     11x11
#define G4_OFF   187    // inv_opt[:11,11:15]   11x4
#define GP_OFF   231    // P^T P                11x11
#define GPD_OFF  352    // Pd^T Pd
#define GPDD_OFF 473    // Pdd^T Pdd
#define WS_FLOATS 594

#define BSTRIDE 308     // row stride (16B aligned)

__device__ void gj_inv(double (*aug)[34], int N, double* fac, int* piv, int tid, int nthr)
{
    for (int k = 0; k < N; ++k) {
        if (tid == 0) {
            int p = k; double best = fabs(aug[k][k]);
            for (int r = k + 1; r < N; ++r) { double v = fabs(aug[r][k]); if (v > best) { best = v; p = r; } }
            *piv = p;
        }
        __syncthreads();
        int p = *piv;
        if (p != k) {
            for (int c = tid; c < 2 * N; c += nthr) { double t = aug[k][c]; aug[k][c] = aug[p][c]; aug[p][c] = t; }
        }
        __syncthreads();
        double pv = aug[k][k];
        __syncthreads();
        for (int c = tid; c < 2 * N; c += nthr) aug[k][c] /= pv;
        __syncthreads();
        if (tid < N) fac[tid] = aug[tid][k];
        __syncthreads();
        for (int idx = tid; idx < N * 2 * N; idx += nthr) {
            int r = idx / (2 * N), c = idx % (2 * N);
            if (r != k) aug[r][c] -= fac[r] * aug[k][c];
        }
        __syncthreads();
    }
}

__global__ __launch_bounds__(128) void setup_kernel(const float* __restrict__ P,
                                                    const float* __restrict__ Pd,
                                                    const float* __restrict__ Pdd,
                                                    float* __restrict__ ws)
{
    __shared__ double G[3][NVARS][NVARS];
    __shared__ double aug[17][34];
    __shared__ double fac[17];
    __shared__ int piv;
    const int tid = threadIdx.x, nthr = 128;

    for (int idx = tid; idx < 3 * 121; idx += nthr) {
        int q = idx / 121, rem = idx % 121, r = rem / 11, c = rem % 11;
        const float* B = (q == 0) ? P : (q == 1) ? Pd : Pdd;
        double s = 0.0;
        for (int t = 0; t < NUMT; ++t) s += (double)B[t * 11 + r] * (double)B[t * 11 + c];
        G[q][r][c] = s;
    }
    __syncthreads();
    for (int idx = tid; idx < 3 * 121; idx += nthr) ws[GP_OFF + idx] = (float)((&G[0][0][0])[idx]);

    for (int idx = tid; idx < 17 * 34; idx += nthr) aug[idx / 34][idx % 34] = 0.0;
    __syncthreads();
    for (int idx = tid; idx < 121; idx += nthr) aug[idx / 11][idx % 11] = G[2][idx / 11][idx % 11];
    if (tid < 66) {
        int r = tid / 11, j = tid % 11;
        const float* src = (r == 0) ? P : (r == 1) ? Pd : (r == 2) ? (P + 99 * 11) : (r == 3) ? (Pd + 99 * 11)
                           : (r == 4) ? (P + 49 * 11) : (P + 74 * 11);
        double v = (double)src[j];
        aug[j][11 + r] = v;
        aug[11 + r][j] = v;
    }
    if (tid < 17) aug[tid][17 + tid] = 1.0;
    __syncthreads();
    gj_inv(aug, 17, fac, &piv, tid, nthr);
    if (tid < 66) { int j = tid / 6, k = tid % 6; ws[E_OFF + tid] = (float)aug[j][17 + 11 + k]; }
    __syncthreads();

    for (int idx = tid; idx < 17 * 34; idx += nthr) aug[idx / 34][idx % 34] = 0.0;
    __syncthreads();
    for (int idx = tid; idx < 121; idx += nthr) {
        int r = idx / 11, c = idx % 11;
        aug[r][c] = 11.0 * G[0][r][c] + G[1][r][c] + G[2][r][c] + ((r == c) ? 1.0 : 0.0);
    }
    if (tid < 44) {
        int r = tid / 11, j = tid % 11;
        const float* src = (r == 0) ? P : (r == 1) ? Pd : (r == 2) ? (P + 99 * 11) : (Pd + 99 * 11);
        double v = (double)src[j];
        aug[j][11 + r] = v;
        aug[11 + r][j] = v;
    }
    if (tid < 15) aug[tid][15 + tid] = 1.0;
    __syncthreads();
    gj_inv(aug, 15, fac, &piv, tid, nthr);
    if (tid < 121) { int j = tid / 11, k = tid % 11; ws[F_OFF + tid] = (float)aug[j][15 + k]; }
    if (tid < 44)  { int j = tid / 4,  k = tid % 4;  ws[G4_OFF + tid] = (float)aug[j][15 + 11 + k]; }
}

__device__ __forceinline__ float sbcast(float v) {
    return __int_as_float(__builtin_amdgcn_readfirstlane(__float_as_int(v)));
}

// solve: 1 element per 256-thread block, grid 2048; balanced wave layout:
//   wave0: A(t=0..63)   wave1: A(t=64..99)
//   wave2: Gram (||A) + B tasks 0..32
//   wave3: B tasks 33..65 + C + D (+ c_bar init, out write)
// __launch_bounds__(256) with NO min-waves arg: allocator unconstrained
// (natural demand ~52 VGPR <= 64 -> HW allows 8 waves/SIMD; min-waves arg N
// sets a 256/N VGPR budget on this toolchain -> N>=5 forces spill: r5..r9).
__global__ __launch_bounds__(256) void solve_kernel(
    const float* __restrict__ P, const float* __restrict__ Pd, const float* __restrict__ Pdd,
    const float* __restrict__ ise, const float* __restrict__ term, const float* __restrict__ via,
    const float* __restrict__ obs, const float* __restrict__ tgt, const float* __restrict__ dtb,
    const float* __restrict__ ws, float* __restrict__ out)
{
    __shared__ __align__(16) float sBc[NVARS][BSTRIDE];   // [j][q*100+t]
    __shared__ __align__(16) float wbc[2][BSTRIDE];       // [axis][q*100+t]
    __shared__ float cst[WS_FLOATS];
    __shared__ float sd456[3][24];    // Gram matvec results (wave 2)
    __shared__ float Dred[6][12];
    __shared__ float mlin[2][12];
    __shared__ float scoef[2][12];
    __shared__ float beqs[2][4];
    __shared__ float sobs[2][NOBS];
    __shared__ float stgt[6];

    const int tid = threadIdx.x;
    const int b = blockIdx.x;

    // ---- stage LDS
    for (int idx = tid; idx < NVARS * BSTRIDE; idx += 256) {
        int j = idx / BSTRIDE, r = idx % BSTRIDE;
        float v = 0.f;
        if (r < 300) {
            int q = r / 100, t = r % 100;
            const float* Bq = (q == 0) ? P : (q == 1) ? Pd : Pdd;
            v = Bq[t * 11 + j];
        }
        sBc[j][r] = v;
    }
    for (int idx = tid; idx < WS_FLOATS; idx += 256) cst[idx] = ws[idx];
    if (tid < 20) sobs[tid / 10][tid % 10] = obs[b * 20 + tid];
    if (tid == 0) {
        beqs[0][0] = 0.f; beqs[0][1] = ise[b*4+2]; beqs[0][2] = term[b*4+0]; beqs[0][3] = term[b*4+2];
        beqs[1][0] = 0.f; beqs[1][1] = ise[b*4+3]; beqs[1][2] = term[b*4+1]; beqs[1][3] = term[b*4+3];
        stgt[0] = tgt[b*4+0]; stgt[1] = tgt[b*4+2];
        stgt[2] = tgt[b*4+1]; stgt[3] = tgt[b*4+3];
        stgt[4] = dtb[b*2+0]; stgt[5] = dtb[b*2+1];
    }
    __syncthreads();

    // lane roles
    const int l2 = tid - 128;   // wave-2 local (Gram: l2<22, B: l2<33)
    const int l3 = tid - 192;   // wave-3 local (B: l3<33 -> tasks 33.., C/D: l3<22)
    const int ca = (l3 >= 0) ? l3 / 11 : 0, cj = (l3 >= 0) ? l3 % 11 : 0;

    // init c_bar (r1-verbatim) on wave 3
    float lm = 0.f, cb = 0.f;
    if (l3 >= 0 && l3 < 22) {
        float bi0 = 0.f, bi1 = beqs[ca][1], bi2 = beqs[ca][2], bi3 = beqs[ca][3];
        float bi4 = via[b*4 + 2*ca + 0], bi5 = via[b*4 + 2*ca + 1];
        const float* E = &cst[E_OFF + cj * 6];
        float s = E[0]*bi0 + E[1]*bi1 + E[2]*bi2 + E[3]*bi3 + E[4]*bi4 + E[5]*bi5;
        cb = s; scoef[ca][cj] = s;
    }

    // ---- iteration-invariant caches (phase A lanes): full basis rows in VGPRs
    float rP[NVARS], rPd[NVARS], rPdd[NVARS];
    {
        const int t = (tid < NUMT) ? tid : 0;
        #pragma unroll
        for (int k = 0; k < NVARS; ++k) {
            rP[k]   = sBc[k][t];
            rPd[k]  = sBc[k][t + 100];
            rPdd[k] = sBc[k][t + 200];
        }
    }
    float obx[NOBS], oby[NOBS];   // wave-uniform -> SGPRs
    #pragma unroll
    for (int o = 0; o < NOBS; ++o) {
        obx[o] = sbcast(sobs[0][o]);
        oby[o] = sbcast(sobs[1][o]);
    }
    const float tg0 = sbcast(stgt[0]), tg1 = sbcast(stgt[1]);
    const float tg2 = sbcast(stgt[2]), tg3 = sbcast(stgt[3]);
    const float tg4 = sbcast(stgt[4]), tg5 = sbcast(stgt[5]);

    float* pwA = &wbc[0][tid];               // + axis*BSTRIDE + q*100

    // phase-B task: wave2 lanes 0..32 -> tasks 0..32; wave3 lanes 0..32 -> tasks 33..65
    int btask = -1;
    if (l2 >= 0 && l2 < 33) btask = l2;
    if (l3 >= 0 && l3 < 33) btask = l3 + 33;
    const int wi = (btask >= 0) ? btask % 6 : 0;
    const int bjj = (btask >= 0) ? btask / 6 : 0;
    const float4* pbB = (const float4*)(&sBc[0][0] + bjj * BSTRIDE + (wi % 3) * 100);
    const float4* pwB = (const float4*)(&wbc[wi / 3][(wi % 3) * 100]);
    __syncthreads();

    for (int it = 0; it < MAXIT; ++it) {
        // ---- phase A (waves 0,1: tid<100) — r4-verbatim math
        if (tid < NUMT) {
            float x=0,y=0,xd=0,yd=0,xdd=0,ydd=0;
            #pragma unroll
            for (int k = 0; k < NVARS; ++k) {
                float cxk = scoef[0][k], cyk = scoef[1][k];
                x += cxk*rP[k];   y += cyk*rP[k];
                xd += cxk*rPd[k]; yd += cyk*rPd[k];
                xdd += cxk*rPdd[k]; ydd += cyk*rPdd[k];
            }
            float Sbx = 0.f, Sby = 0.f;
            #pragma unroll
            for (int o = 0; o < NOBS; ++o) {
                float dx = x - obx[o], dy = y - oby[o];
                float r2 = dx*dx + dy*dy;
                float f  = fmaxf(1.0f, 0.4f * rsqrtf(fmaxf(r2, 1e-30f)));
                Sbx += fmaf(dx, f, obx[o]);
                Sby += fmaf(dy, f, oby[o]);
            }
            float rv = sqrtf(xd*xd + yd*yd);
            float fv = fminf(fmaxf(rv, 0.1f), 2.0f) / fmaxf(rv, 1e-30f);
            float ra = sqrtf(xdd*xdd + ydd*ydd);
            float fa = fminf(ra, 2.0f) / fmaxf(ra, 1e-30f);
            float tt = (float)tid * (5.0f / 99.0f);
            float xt = tg0 + tg1*tt, yt = tg2 + tg3*tt;
            float wct = x - xt, wst = y - yt;
            float rt = sqrtf(wct*wct + wst*wst);
            float ftg = fminf(fmaxf(rt, tg4), tg5) / fmaxf(rt, 1e-30f);
            pwA[0]   = Sbx + xt + wct*ftg;
            pwA[100] = xd * fv;
            pwA[200] = xdd * fa;
            pwA[BSTRIDE]       = Sby + yt + wst*ftg;
            pwA[BSTRIDE + 100] = yd * fv;
            pwA[BSTRIDE + 200] = ydd * fa;
        }
        // ---- wave 2 concurrently: Gram matvecs from prev coef (bit-exact)
        if (l2 >= 0 && l2 < 22) {
            const int ga = l2 / 11, gj = l2 % 11;
            float d4=0.f, d5=0.f, d6=0.f;
            #pragma unroll
            for (int k = 0; k < 11; ++k) {
                float ck = scoef[ga][k];
                d4 += ck * cst[GP_OFF   + k*11 + gj];
                d5 += ck * cst[GPD_OFF  + k*11 + gj];
                d6 += ck * cst[GPDD_OFF + k*11 + gj];
            }
            sd456[0][l2] = d4; sd456[1][l2] = d5; sd456[2][l2] = d6;
        }
        __syncthreads();

        // ---- phase B (waves 2,3): 66 float4 dots, exact t-order
        if (btask >= 0) {
            float s = 0.f;
            #pragma unroll
            for (int i = 0; i < 25; ++i) {
                float4 a = pbB[i], w = pwB[i];
                s += w.x * a.x; s += w.y * a.y; s += w.z * a.z; s += w.w * a.w;
            }
            Dred[wi][bjj] = s;
        }
        __syncthreads();

        // ---- phase C (wave 3, l3<22): combine
        if (l3 >= 0 && l3 < 22) {
            float d4 = sd456[0][l3], d5 = sd456[1][l3], d6 = sd456[2][l3];
            int i0 = 3*ca;
            float D0 = Dred[i0][cj], D1 = Dred[i0+1][cj], D2 = Dred[i0+2][cj];
            lm -= (11.f*d4 - D0) + (d5 - D1) + (d6 - D2);
            mlin[ca][cj] = lm + D0 + D1 + D2 + cb;
        }
        // no barrier: C->D producers/consumers are lanes l3<22 of wave 3

        // ---- phase D (wave 3, l3<22)
        if (l3 >= 0 && l3 < 22) {
            float s = 0.f;
            #pragma unroll
            for (int k = 0; k < 11; ++k) s += cst[F_OFF + cj*11 + k] * mlin[ca][k];
            #pragma unroll
            for (int k = 0; k < 4; ++k)  s += cst[G4_OFF + cj*4 + k] * beqs[ca][k];
            scoef[ca][cj] = s;
        }
        __syncthreads();
    }

    if (l3 >= 0 && l3 < 22) out[b * 22 + l3] = scoef[ca][cj];
}

extern "C" void kernel_launch(void* const* d_in, const int* in_sizes, int n_in,
                              void* d_out, int out_size, void* d_ws, size_t ws_size,
                              hipStream_t stream)
{
    const float* P    = (const float*)d_in[0];
    const float* Pd   = (const float*)d_in[1];
    const float* Pdd  = (const float*)d_in[2];
    const float* ise  = (const float*)d_in[3];
    const float* term = (const float*)d_in[4];
    const float* via  = (const float*)d_in[5];
    const float* obs  = (const float*)d_in[6];
    const float* tgt  = (const float*)d_in[7];
    const float* dtb  = (const float*)d_in[8];
    float* ws  = (float*)d_ws;
    float* out = (float*)d_out;

    const int B = in_sizes[3] / 4;   // 2048

    hipLaunchKernelGGL(setup_kernel, dim3(1), dim3(128), 0, stream, P, Pd, Pdd, ws);
    hipLaunchKernelGGL(solve_kernel, dim3(B), dim3(256), 0, stream,
                       P, Pd, Pdd, ise, term, via, obs, tgt, dtb, ws, out);
}

// Round 11
// 287.808 us; speedup vs baseline: 1.1571x; 1.0309x over previous
//
#include <hip/hip_runtime.h>
#include <math.h>

#define NVARS 11
#define NUMT  100
#define NOBS  10
#define MAXIT 50

// workspace layout (floats) — identical to r1..r10
#define E_OFF    0      // inv_init[:11,11:17]  11x6
#define F_OFF    66     // inv_opt[:11,:11]     11x11
#define G4_OFF   187    // inv_opt[:11,11:15]   11x4
#define GP_OFF   231    // P^T P                11x11
#define GPD_OFF  352    // Pd^T Pd
#define GPDD_OFF 473    // Pdd^T Pdd
#define WS_FLOATS 594

#define BSTRIDE 308     // row stride (16B aligned)

__device__ void gj_inv(double (*aug)[34], int N, double* fac, int* piv, int tid, int nthr)
{
    for (int k = 0; k < N; ++k) {
        if (tid == 0) {
            int p = k; double best = fabs(aug[k][k]);
            for (int r = k + 1; r < N; ++r) { double v = fabs(aug[r][k]); if (v > best) { best = v; p = r; } }
            *piv = p;
        }
        __syncthreads();
        int p = *piv;
        if (p != k) {
            for (int c = tid; c < 2 * N; c += nthr) { double t = aug[k][c]; aug[k][c] = aug[p][c]; aug[p][c] = t; }
        }
        __syncthreads();
        double pv = aug[k][k];
        __syncthreads();
        for (int c = tid; c < 2 * N; c += nthr) aug[k][c] /= pv;
        __syncthreads();
        if (tid < N) fac[tid] = aug[tid][k];
        __syncthreads();
        for (int idx = tid; idx < N * 2 * N; idx += nthr) {
            int r = idx / (2 * N), c = idx % (2 * N);
            if (r != k) aug[r][c] -= fac[r] * aug[k][c];
        }
        __syncthreads();
    }
}

__global__ __launch_bounds__(128) void setup_kernel(const float* __restrict__ P,
                                                    const float* __restrict__ Pd,
                                                    const float* __restrict__ Pdd,
                                                    float* __restrict__ ws)
{
    __shared__ double G[3][NVARS][NVARS];
    __shared__ double aug[17][34];
    __shared__ double fac[17];
    __shared__ int piv;
    const int tid = threadIdx.x, nthr = 128;

    for (int idx = tid; idx < 3 * 121; idx += nthr) {
        int q = idx / 121, rem = idx % 121, r = rem / 11, c = rem % 11;
        const float* B = (q == 0) ? P : (q == 1) ? Pd : Pdd;
        double s = 0.0;
        for (int t = 0; t < NUMT; ++t) s += (double)B[t * 11 + r] * (double)B[t * 11 + c];
        G[q][r][c] = s;
    }
    __syncthreads();
    for (int idx = tid; idx < 3 * 121; idx += nthr) ws[GP_OFF + idx] = (float)((&G[0][0][0])[idx]);

    for (int idx = tid; idx < 17 * 34; idx += nthr) aug[idx / 34][idx % 34] = 0.0;
    __syncthreads();
    for (int idx = tid; idx < 121; idx += nthr) aug[idx / 11][idx % 11] = G[2][idx / 11][idx % 11];
    if (tid < 66) {
        int r = tid / 11, j = tid % 11;
        const float* src = (r == 0) ? P : (r == 1) ? Pd : (r == 2) ? (P + 99 * 11) : (r == 3) ? (Pd + 99 * 11)
                           : (r == 4) ? (P + 49 * 11) : (P + 74 * 11);
        double v = (double)src[j];
        aug[j][11 + r] = v;
        aug[11 + r][j] = v;
    }
    if (tid < 17) aug[tid][17 + tid] = 1.0;
    __syncthreads();
    gj_inv(aug, 17, fac, &piv, tid, nthr);
    if (tid < 66) { int j = tid / 6, k = tid % 6; ws[E_OFF + tid] = (float)aug[j][17 + 11 + k]; }
    __syncthreads();

    for (int idx = tid; idx < 17 * 34; idx += nthr) aug[idx / 34][idx % 34] = 0.0;
    __syncthreads();
    for (int idx = tid; idx < 121; idx += nthr) {
        int r = idx / 11, c = idx % 11;
        aug[r][c] = 11.0 * G[0][r][c] + G[1][r][c] + G[2][r][c] + ((r == c) ? 1.0 : 0.0);
    }
    if (tid < 44) {
        int r = tid / 11, j = tid % 11;
        const float* src = (r == 0) ? P : (r == 1) ? Pd : (r == 2) ? (P + 99 * 11) : (Pd + 99 * 11);
        double v = (double)src[j];
        aug[j][11 + r] = v;
        aug[11 + r][j] = v;
    }
    if (tid < 15) aug[tid][15 + tid] = 1.0;
    __syncthreads();
    gj_inv(aug, 15, fac, &piv, tid, nthr);
    if (tid < 121) { int j = tid / 11, k = tid % 11; ws[F_OFF + tid] = (float)aug[j][15 + k]; }
    if (tid < 44)  { int j = tid / 4,  k = tid % 4;  ws[G4_OFF + tid] = (float)aug[j][15 + 11 + k]; }
}

__device__ __forceinline__ float sbcast(float v) {
    return __int_as_float(__builtin_amdgcn_readfirstlane(__float_as_int(v)));
}

// solve: 1 element per 256-thread block, grid 2048; balanced wave layout:
//   wave0: A(t=0..63)   wave1: A(t=64..99)
//   wave2: Gram (||A) + B tasks 0..32
//   wave3: B tasks 33..65 + C + D (+ c_bar init, out write)
// Occupancy law (r1..r10): waves/SIMD = min(floor(256/VGPR), min_waves_arg);
// allocator budget under (256,w) = 256/w. Target: 5 waves/SIMD @ <=51 VGPR.
// rP/rPd cached in VGPRs; Pdd read from LDS (r7's bit-exact trim) -> demand ~45-48.
__global__ __launch_bounds__(256, 5) void solve_kernel(
    const float* __restrict__ P, const float* __restrict__ Pd, const float* __restrict__ Pdd,
    const float* __restrict__ ise, const float* __restrict__ term, const float* __restrict__ via,
    const float* __restrict__ obs, const float* __restrict__ tgt, const float* __restrict__ dtb,
    const float* __restrict__ ws, float* __restrict__ out)
{
    __shared__ __align__(16) float sBc[NVARS][BSTRIDE];   // [j][q*100+t]
    __shared__ __align__(16) float wbc[2][BSTRIDE];       // [axis][q*100+t]
    __shared__ float cst[WS_FLOATS];
    __shared__ float sd456[3][24];    // Gram matvec results (wave 2)
    __shared__ float Dred[6][12];
    __shared__ float mlin[2][12];
    __shared__ float scoef[2][12];
    __shared__ float beqs[2][4];
    __shared__ float sobs[2][NOBS];
    __shared__ float stgt[6];

    const int tid = threadIdx.x;
    const int b = blockIdx.x;

    // ---- stage LDS
    for (int idx = tid; idx < NVARS * BSTRIDE; idx += 256) {
        int j = idx / BSTRIDE, r = idx % BSTRIDE;
        float v = 0.f;
        if (r < 300) {
            int q = r / 100, t = r % 100;
            const float* Bq = (q == 0) ? P : (q == 1) ? Pd : Pdd;
            v = Bq[t * 11 + j];
        }
        sBc[j][r] = v;
    }
    for (int idx = tid; idx < WS_FLOATS; idx += 256) cst[idx] = ws[idx];
    if (tid < 20) sobs[tid / 10][tid % 10] = obs[b * 20 + tid];
    if (tid == 0) {
        beqs[0][0] = 0.f; beqs[0][1] = ise[b*4+2]; beqs[0][2] = term[b*4+0]; beqs[0][3] = term[b*4+2];
        beqs[1][0] = 0.f; beqs[1][1] = ise[b*4+3]; beqs[1][2] = term[b*4+1]; beqs[1][3] = term[b*4+3];
        stgt[0] = tgt[b*4+0]; stgt[1] = tgt[b*4+2];
        stgt[2] = tgt[b*4+1]; stgt[3] = tgt[b*4+3];
        stgt[4] = dtb[b*2+0]; stgt[5] = dtb[b*2+1];
    }
    __syncthreads();

    // lane roles
    const int l2 = tid - 128;   // wave-2 local (Gram: l2<22, B: l2<33)
    const int l3 = tid - 192;   // wave-3 local (B: l3<33 -> tasks 33.., C/D: l3<22)
    const int ca = (l3 >= 0) ? l3 / 11 : 0, cj = (l3 >= 0) ? l3 % 11 : 0;

    // init c_bar (r1-verbatim) on wave 3
    float lm = 0.f, cb = 0.f;
    if (l3 >= 0 && l3 < 22) {
        float bi0 = 0.f, bi1 = beqs[ca][1], bi2 = beqs[ca][2], bi3 = beqs[ca][3];
        float bi4 = via[b*4 + 2*ca + 0], bi5 = via[b*4 + 2*ca + 1];
        const float* E = &cst[E_OFF + cj * 6];
        float s = E[0]*bi0 + E[1]*bi1 + E[2]*bi2 + E[3]*bi3 + E[4]*bi4 + E[5]*bi5;
        cb = s; scoef[ca][cj] = s;
    }

    // ---- iteration-invariant caches (phase A lanes): rP, rPd in VGPRs; Pdd via LDS
    const int tA = (tid < NUMT) ? tid : 0;
    const float* ptA = &sBc[0][tA];           // + k*BSTRIDE (+100/+200)
    float rP[NVARS], rPd[NVARS];
    #pragma unroll
    for (int k = 0; k < NVARS; ++k) {
        rP[k]  = ptA[k * BSTRIDE];
        rPd[k] = ptA[k * BSTRIDE + 100];
    }
    float obx[NOBS], oby[NOBS];   // wave-uniform -> SGPRs
    #pragma unroll
    for (int o = 0; o < NOBS; ++o) {
        obx[o] = sbcast(sobs[0][o]);
        oby[o] = sbcast(sobs[1][o]);
    }
    const float tg0 = sbcast(stgt[0]), tg1 = sbcast(stgt[1]);
    const float tg2 = sbcast(stgt[2]), tg3 = sbcast(stgt[3]);
    const float tg4 = sbcast(stgt[4]), tg5 = sbcast(stgt[5]);

    float* pwA = &wbc[0][tid];               // + axis*BSTRIDE + q*100

    // phase-B task: wave2 lanes 0..32 -> tasks 0..32; wave3 lanes 0..32 -> tasks 33..65
    int btask = -1;
    if (l2 >= 0 && l2 < 33) btask = l2;
    if (l3 >= 0 && l3 < 33) btask = l3 + 33;
    const int wi = (btask >= 0) ? btask % 6 : 0;
    const int bjj = (btask >= 0) ? btask / 6 : 0;
    const float4* pbB = (const float4*)(&sBc[0][0] + bjj * BSTRIDE + (wi % 3) * 100);
    const float4* pwB = (const float4*)(&wbc[wi / 3][(wi % 3) * 100]);
    __syncthreads();

    for (int it = 0; it < MAXIT; ++it) {
        // ---- phase A (waves 0,1: tid<100) — r4-verbatim math; Pdd from LDS (same bits)
        if (tid < NUMT) {
            float x=0,y=0,xd=0,yd=0,xdd=0,ydd=0;
            #pragma unroll
            for (int k = 0; k < NVARS; ++k) {
                float cxk = scoef[0][k], cyk = scoef[1][k];
                float pdd = ptA[k * BSTRIDE + 200];
                x += cxk*rP[k];   y += cyk*rP[k];
                xd += cxk*rPd[k]; yd += cyk*rPd[k];
                xdd += cxk*pdd;   ydd += cyk*pdd;
            }
            float Sbx = 0.f, Sby = 0.f;
            #pragma unroll
            for (int o = 0; o < NOBS; ++o) {
                float dx = x - obx[o], dy = y - oby[o];
                float r2 = dx*dx + dy*dy;
                float f  = fmaxf(1.0f, 0.4f * rsqrtf(fmaxf(r2, 1e-30f)));
                Sbx += fmaf(dx, f, obx[o]);
                Sby += fmaf(dy, f, oby[o]);
            }
            float rv = sqrtf(xd*xd + yd*yd);
            float fv = fminf(fmaxf(rv, 0.1f), 2.0f) / fmaxf(rv, 1e-30f);
            float ra = sqrtf(xdd*xdd + ydd*ydd);
            float fa = fminf(ra, 2.0f) / fmaxf(ra, 1e-30f);
            float tt = (float)tid * (5.0f / 99.0f);
            float xt = tg0 + tg1*tt, yt = tg2 + tg3*tt;
            float wct = x - xt, wst = y - yt;
            float rt = sqrtf(wct*wct + wst*wst);
            float ftg = fminf(fmaxf(rt, tg4), tg5) / fmaxf(rt, 1e-30f);
            pwA[0]   = Sbx + xt + wct*ftg;
            pwA[100] = xd * fv;
            pwA[200] = xdd * fa;
            pwA[BSTRIDE]       = Sby + yt + wst*ftg;
            pwA[BSTRIDE + 100] = yd * fv;
            pwA[BSTRIDE + 200] = ydd * fa;
        }
        // ---- wave 2 concurrently: Gram matvecs from prev coef (bit-exact)
        if (l2 >= 0 && l2 < 22) {
            const int ga = l2 / 11, gj = l2 % 11;
            float d4=0.f, d5=0.f, d6=0.f;
            #pragma unroll
            for (int k = 0; k < 11; ++k) {
                float ck = scoef[ga][k];
                d4 += ck * cst[GP_OFF   + k*11 + gj];
                d5 += ck * cst[GPD_OFF  + k*11 + gj];
                d6 += ck * cst[GPDD_OFF + k*11 + gj];
            }
            sd456[0][l2] = d4; sd456[1][l2] = d5; sd456[2][l2] = d6;
        }
        __syncthreads();

        // ---- phase B (waves 2,3): 66 float4 dots, exact t-order
        if (btask >= 0) {
            float s = 0.f;
            #pragma unroll
            for (int i = 0; i < 25; ++i) {
                float4 a = pbB[i], w = pwB[i];
                s += w.x * a.x; s += w.y * a.y; s += w.z * a.z; s += w.w * a.w;
            }
            Dred[wi][bjj] = s;
        }
        __syncthreads();

        // ---- phase C (wave 3, l3<22): combine
        if (l3 >= 0 && l3 < 22) {
            float d4 = sd456[0][l3], d5 = sd456[1][l3], d6 = sd456[2][l3];
            int i0 = 3*ca;
            float D0 = Dred[i0][cj], D1 = Dred[i0+1][cj], D2 = Dred[i0+2][cj];
            lm -= (11.f*d4 - D0) + (d5 - D1) + (d6 - D2);
            mlin[ca][cj] = lm + D0 + D1 + D2 + cb;
        }
        // no barrier: C->D producers/consumers are lanes l3<22 of wave 3

        // ---- phase D (wave 3, l3<22)
        if (l3 >= 0 && l3 < 22) {
            float s = 0.f;
            #pragma unroll
            for (int k = 0; k < 11; ++k) s += cst[F_OFF + cj*11 + k] * mlin[ca][k];
            #pragma unroll
            for (int k = 0; k < 4; ++k)  s += cst[G4_OFF + cj*4 + k] * beqs[ca][k];
            scoef[ca][cj] = s;
        }
        __syncthreads();
    }

    if (l3 >= 0 && l3 < 22) out[b * 22 + l3] = scoef[ca][cj];
}

extern "C" void kernel_launch(void* const* d_in, const int* in_sizes, int n_in,
                              void* d_out, int out_size, void* d_ws, size_t ws_size,
                              hipStream_t stream)
{
    const float* P    = (const float*)d_in[0];
    const float* Pd   = (const float*)d_in[1];
    const float* Pdd  = (const float*)d_in[2];
    const float* ise  = (const float*)d_in[3];
    const float* term = (const float*)d_in[4];
    const float* via  = (const float*)d_in[5];
    const float* obs  = (const float*)d_in[6];
    const float* tgt  = (const float*)d_in[7];
    const float* dtb  = (const float*)d_in[8];
    float* ws  = (float*)d_ws;
    float* out = (float*)d_out;

    const int B = in_sizes[3] / 4;   // 2048

    hipLaunchKernelGGL(setup_kernel, dim3(1), dim3(128), 0, stream, P, Pd, Pdd, ws);
    hipLaunchKernelGGL(solve_kernel, dim3(B), dim3(256), 0, stream,
                       P, Pd, Pdd, ise, term, via, obs, tgt, dtb, ws, out);
}

// Round 12
// 240.696 us; speedup vs baseline: 1.3835x; 1.1957x over previous
//
#include <hip/hip_runtime.h>
#include <math.h>

#define NVARS 11
#define NUMT  100
#define NOBS  10
#define MAXIT 50

// workspace layout (floats) — identical to r1..r11
#define E_OFF    0      // inv_init[:11,11:17]  11x6
#define F_OFF    66     // inv_opt[:11,:11]     11x11
#define G4_OFF   187    // inv_opt[:11,11:15]   11x4
#define GP_OFF   231    // P^T P                11x11
#define GPD_OFF  352    // Pd^T Pd
#define GPDD_OFF 473    // Pdd^T Pdd
#define WS_FLOATS 594

#define BSTRIDE 308     // row stride (16B aligned)

__device__ void gj_inv(double (*aug)[34], int N, double* fac, int* piv, int tid, int nthr)
{
    for (int k = 0; k < N; ++k) {
        if (tid == 0) {
            int p = k; double best = fabs(aug[k][k]);
            for (int r = k + 1; r < N; ++r) { double v = fabs(aug[r][k]); if (v > best) { best = v; p = r; } }
            *piv = p;
        }
        __syncthreads();
        int p = *piv;
        if (p != k) {
            for (int c = tid; c < 2 * N; c += nthr) { double t = aug[k][c]; aug[k][c] = aug[p][c]; aug[p][c] = t; }
        }
        __syncthreads();
        double pv = aug[k][k];
        __syncthreads();
        for (int c = tid; c < 2 * N; c += nthr) aug[k][c] /= pv;
        __syncthreads();
        if (tid < N) fac[tid] = aug[tid][k];
        __syncthreads();
        for (int idx = tid; idx < N * 2 * N; idx += nthr) {
            int r = idx / (2 * N), c = idx % (2 * N);
            if (r != k) aug[r][c] -= fac[r] * aug[k][c];
        }
        __syncthreads();
    }
}

__global__ __launch_bounds__(128) void setup_kernel(const float* __restrict__ P,
                                                    const float* __restrict__ Pd,
                                                    const float* __restrict__ Pdd,
                                                    float* __restrict__ ws)
{
    __shared__ double G[3][NVARS][NVARS];
    __shared__ double aug[17][34];
    __shared__ double fac[17];
    __shared__ int piv;
    const int tid = threadIdx.x, nthr = 128;

    for (int idx = tid; idx < 3 * 121; idx += nthr) {
        int q = idx / 121, rem = idx % 121, r = rem / 11, c = rem % 11;
        const float* B = (q == 0) ? P : (q == 1) ? Pd : Pdd;
        double s = 0.0;
        for (int t = 0; t < NUMT; ++t) s += (double)B[t * 11 + r] * (double)B[t * 11 + c];
        G[q][r][c] = s;
    }
    __syncthreads();
    for (int idx = tid; idx < 3 * 121; idx += nthr) ws[GP_OFF + idx] = (float)((&G[0][0][0])[idx]);

    for (int idx = tid; idx < 17 * 34; idx += nthr) aug[idx / 34][idx % 34] = 0.0;
    __syncthreads();
    for (int idx = tid; idx < 121; idx += nthr) aug[idx / 11][idx % 11] = G[2][idx / 11][idx % 11];
    if (tid < 66) {
        int r = tid / 11, j = tid % 11;
        const float* src = (r == 0) ? P : (r == 1) ? Pd : (r == 2) ? (P + 99 * 11) : (r == 3) ? (Pd + 99 * 11)
                           : (r == 4) ? (P + 49 * 11) : (P + 74 * 11);
        double v = (double)src[j];
        aug[j][11 + r] = v;
        aug[11 + r][j] = v;
    }
    if (tid < 17) aug[tid][17 + tid] = 1.0;
    __syncthreads();
    gj_inv(aug, 17, fac, &piv, tid, nthr);
    if (tid < 66) { int j = tid / 6, k = tid % 6; ws[E_OFF + tid] = (float)aug[j][17 + 11 + k]; }
    __syncthreads();

    for (int idx = tid; idx < 17 * 34; idx += nthr) aug[idx / 34][idx % 34] = 0.0;
    __syncthreads();
    for (int idx = tid; idx < 121; idx += nthr) {
        int r = idx / 11, c = idx % 11;
        aug[r][c] = 11.0 * G[0][r][c] + G[1][r][c] + G[2][r][c] + ((r == c) ? 1.0 : 0.0);
    }
    if (tid < 44) {
        int r = tid / 11, j = tid % 11;
        const float* src = (r == 0) ? P : (r == 1) ? Pd : (r == 2) ? (P + 99 * 11) : (Pd + 99 * 11);
        double v = (double)src[j];
        aug[j][11 + r] = v;
        aug[11 + r][j] = v;
    }
    if (tid < 15) aug[tid][15 + tid] = 1.0;
    __syncthreads();
    gj_inv(aug, 15, fac, &piv, tid, nthr);
    if (tid < 121) { int j = tid / 11, k = tid % 11; ws[F_OFF + tid] = (float)aug[j][15 + k]; }
    if (tid < 44)  { int j = tid / 4,  k = tid % 4;  ws[G4_OFF + tid] = (float)aug[j][15 + 11 + k]; }
}

__device__ __forceinline__ float sbcast(float v) {
    return __int_as_float(__builtin_amdgcn_readfirstlane(__float_as_int(v)));
}

// solve: 1 element per 128-thread block (2 waves), grid 2048 = 8 blocks/CU
// -> ALL elements resident in one generation (LDS 19.4KB x 8 = 155.6KB <= 160KB).
// (128,4): VGPR budget 64 >= natural demand ~52 -> no spill; 16 waves/CU.
// Layout: A on tid<100 (both waves); Gram on tid 100..121 (wave1 idle lanes, || A);
//         B split 33/33 (wave0 lanes 0-32, wave1 lanes 64-96); C/D on tid<22.
__global__ __launch_bounds__(128, 4) void solve_kernel(
    const float* __restrict__ P, const float* __restrict__ Pd, const float* __restrict__ Pdd,
    const float* __restrict__ ise, const float* __restrict__ term, const float* __restrict__ via,
    const float* __restrict__ obs, const float* __restrict__ tgt, const float* __restrict__ dtb,
    const float* __restrict__ ws, float* __restrict__ out)
{
    __shared__ __align__(16) float sBc[NVARS][BSTRIDE];   // [j][q*100+t]
    __shared__ __align__(16) float wbc[2][BSTRIDE];       // [axis][q*100+t]
    __shared__ float cst[WS_FLOATS];
    __shared__ float sd456[3][24];    // Gram matvec results (tid 100..121)
    __shared__ float Dred[6][12];
    __shared__ float mlin[2][12];
    __shared__ float scoef[2][12];
    __shared__ float beqs[2][4];
    __shared__ float sobs[2][NOBS];
    __shared__ float stgt[6];

    const int tid = threadIdx.x;
    const int b = blockIdx.x;

    // ---- stage LDS
    for (int idx = tid; idx < NVARS * BSTRIDE; idx += 128) {
        int j = idx / BSTRIDE, r = idx % BSTRIDE;
        float v = 0.f;
        if (r < 300) {
            int q = r / 100, t = r % 100;
            const float* Bq = (q == 0) ? P : (q == 1) ? Pd : Pdd;
            v = Bq[t * 11 + j];
        }
        sBc[j][r] = v;
    }
    for (int idx = tid; idx < WS_FLOATS; idx += 128) cst[idx] = ws[idx];
    if (tid < 20) sobs[tid / 10][tid % 10] = obs[b * 20 + tid];
    if (tid == 0) {
        beqs[0][0] = 0.f; beqs[0][1] = ise[b*4+2]; beqs[0][2] = term[b*4+0]; beqs[0][3] = term[b*4+2];
        beqs[1][0] = 0.f; beqs[1][1] = ise[b*4+3]; beqs[1][2] = term[b*4+1]; beqs[1][3] = term[b*4+3];
        stgt[0] = tgt[b*4+0]; stgt[1] = tgt[b*4+2];
        stgt[2] = tgt[b*4+1]; stgt[3] = tgt[b*4+3];
        stgt[4] = dtb[b*2+0]; stgt[5] = dtb[b*2+1];
    }
    __syncthreads();

    // init c_bar (r1-verbatim), lanes tid<22 (wave 0)
    const int ca = tid / 11, cj = tid % 11;   // valid for tid<22
    float lm = 0.f, cb = 0.f;
    if (tid < 22) {
        float bi0 = 0.f, bi1 = beqs[ca][1], bi2 = beqs[ca][2], bi3 = beqs[ca][3];
        float bi4 = via[b*4 + 2*ca + 0], bi5 = via[b*4 + 2*ca + 1];
        const float* E = &cst[E_OFF + cj * 6];
        float s = E[0]*bi0 + E[1]*bi1 + E[2]*bi2 + E[3]*bi3 + E[4]*bi4 + E[5]*bi5;
        cb = s; scoef[ca][cj] = s;
    }

    // ---- iteration-invariant caches (phase A lanes): full basis rows in VGPRs (r4-verbatim)
    float rP[NVARS], rPd[NVARS], rPdd[NVARS];
    {
        const int t = (tid < NUMT) ? tid : 0;
        #pragma unroll
        for (int k = 0; k < NVARS; ++k) {
            rP[k]   = sBc[k][t];
            rPd[k]  = sBc[k][t + 100];
            rPdd[k] = sBc[k][t + 200];
        }
    }
    float obx[NOBS], oby[NOBS];   // wave-uniform -> SGPRs
    #pragma unroll
    for (int o = 0; o < NOBS; ++o) {
        obx[o] = sbcast(sobs[0][o]);
        oby[o] = sbcast(sobs[1][o]);
    }
    const float tg0 = sbcast(stgt[0]), tg1 = sbcast(stgt[1]);
    const float tg2 = sbcast(stgt[2]), tg3 = sbcast(stgt[3]);
    const float tg4 = sbcast(stgt[4]), tg5 = sbcast(stgt[5]);

    float* pwA = &wbc[0][tid];               // + axis*BSTRIDE + q*100
    const int lg = tid - 100;                // Gram lane (0..21), wave-1 idle lanes

    // phase-B task: wave0 lanes 0..32 -> tasks 0..32; wave1 lanes 64..96 -> tasks 33..65
    int btask = -1;
    if (tid <= 32) btask = tid;
    else if (tid >= 64 && tid <= 96) btask = tid - 31;
    const int wi = (btask >= 0) ? btask % 6 : 0;
    const int bjj = (btask >= 0) ? btask / 6 : 0;
    const float4* pbB = (const float4*)(&sBc[0][0] + bjj * BSTRIDE + (wi % 3) * 100);
    const float4* pwB = (const float4*)(&wbc[wi / 3][(wi % 3) * 100]);
    __syncthreads();

    for (int it = 0; it < MAXIT; ++it) {
        // ---- phase A (tid<100) — r4-verbatim math
        if (tid < NUMT) {
            float x=0,y=0,xd=0,yd=0,xdd=0,ydd=0;
            #pragma unroll
            for (int k = 0; k < NVARS; ++k) {
                float cxk = scoef[0][k], cyk = scoef[1][k];
                x += cxk*rP[k];   y += cyk*rP[k];
                xd += cxk*rPd[k]; yd += cyk*rPd[k];
                xdd += cxk*rPdd[k]; ydd += cyk*rPdd[k];
            }
            float Sbx = 0.f, Sby = 0.f;
            #pragma unroll
            for (int o = 0; o < NOBS; ++o) {
                float dx = x - obx[o], dy = y - oby[o];
                float r2 = dx*dx + dy*dy;
                float f  = fmaxf(1.0f, 0.4f * rsqrtf(fmaxf(r2, 1e-30f)));
                Sbx += fmaf(dx, f, obx[o]);
                Sby += fmaf(dy, f, oby[o]);
            }
            float rv = sqrtf(xd*xd + yd*yd);
            float fv = fminf(fmaxf(rv, 0.1f), 2.0f) / fmaxf(rv, 1e-30f);
            float ra = sqrtf(xdd*xdd + ydd*ydd);
            float fa = fminf(ra, 2.0f) / fmaxf(ra, 1e-30f);
            float tt = (float)tid * (5.0f / 99.0f);
            float xt = tg0 + tg1*tt, yt = tg2 + tg3*tt;
            float wct = x - xt, wst = y - yt;
            float rt = sqrtf(wct*wct + wst*wst);
            float ftg = fminf(fmaxf(rt, tg4), tg5) / fmaxf(rt, 1e-30f);
            pwA[0]   = Sbx + xt + wct*ftg;
            pwA[100] = xd * fv;
            pwA[200] = xdd * fa;
            pwA[BSTRIDE]       = Sby + yt + wst*ftg;
            pwA[BSTRIDE + 100] = yd * fv;
            pwA[BSTRIDE + 200] = ydd * fa;
        }
        // ---- Gram matvecs on wave-1 idle lanes (tid 100..121), || A (bit-exact)
        if (lg >= 0 && lg < 22) {
            const int ga = lg / 11, gj = lg % 11;
            float d4=0.f, d5=0.f, d6=0.f;
            #pragma unroll
            for (int k = 0; k < 11; ++k) {
                float ck = scoef[ga][k];
                d4 += ck * cst[GP_OFF   + k*11 + gj];
                d5 += ck * cst[GPD_OFF  + k*11 + gj];
                d6 += ck * cst[GPDD_OFF + k*11 + gj];
            }
            sd456[0][lg] = d4; sd456[1][lg] = d5; sd456[2][lg] = d6;
        }
        __syncthreads();

        // ---- phase B (33 tasks per wave): float4 LDS dots, exact t-order
        if (btask >= 0) {
            float s = 0.f;
            #pragma unroll
            for (int i = 0; i < 25; ++i) {
                float4 a = pbB[i], w = pwB[i];
                s += w.x * a.x; s += w.y * a.y; s += w.z * a.z; s += w.w * a.w;
            }
            Dred[wi][bjj] = s;
        }
        __syncthreads();

        // ---- phase C (tid<22, wave 0): combine
        if (tid < 22) {
            float d4 = sd456[0][tid], d5 = sd456[1][tid], d6 = sd456[2][tid];
            int i0 = 3*ca;
            float D0 = Dred[i0][cj], D1 = Dred[i0+1][cj], D2 = Dred[i0+2][cj];
            lm -= (11.f*d4 - D0) + (d5 - D1) + (d6 - D2);
            mlin[ca][cj] = lm + D0 + D1 + D2 + cb;
        }
        // no barrier: C->D producers/consumers are lanes tid<22 of wave 0

        // ---- phase D (tid<22)
        if (tid < 22) {
            float s = 0.f;
            #pragma unroll
            for (int k = 0; k < 11; ++k) s += cst[F_OFF + cj*11 + k] * mlin[ca][k];
            #pragma unroll
            for (int k = 0; k < 4; ++k)  s += cst[G4_OFF + cj*4 + k] * beqs[ca][k];
            scoef[ca][cj] = s;
        }
        __syncthreads();
    }

    if (tid < 22) out[b * 22 + tid] = scoef[ca][cj];
}

extern "C" void kernel_launch(void* const* d_in, const int* in_sizes, int n_in,
                              void* d_out, int out_size, void* d_ws, size_t ws_size,
                              hipStream_t stream)
{
    const float* P    = (const float*)d_in[0];
    const float* Pd   = (const float*)d_in[1];
    const float* Pdd  = (const float*)d_in[2];
    const float* ise  = (const float*)d_in[3];
    const float* term = (const float*)d_in[4];
    const float* via  = (const float*)d_in[5];
    const float* obs  = (const float*)d_in[6];
    const float* tgt  = (const float*)d_in[7];
    const float* dtb  = (const float*)d_in[8];
    float* ws  = (float*)d_ws;
    float* out = (float*)d_out;

    const int B = in_sizes[3] / 4;   // 2048

    hipLaunchKernelGGL(setup_kernel, dim3(1), dim3(128), 0, stream, P, Pd, Pdd, ws);
    hipLaunchKernelGGL(solve_kernel, dim3(B), dim3(128), 0, stream,
                       P, Pd, Pdd, ise, term, via, obs, tgt, dtb, ws, out);
}